// Round 3
// baseline (166.838 us; speedup 1.0000x reference)
//
#include <hip/hip_runtime.h>

// RBF Gram: out[i,j] = exp(-0.5 * ||x_i - x_j||^2), x: [N,64] fp32, N=8192.
// d2 = ||xi||^2 + ||xj||^2 - 2<xi,xj>; dot via 64x64 LDS-tiled outer-product FMA.

#define GAMMA 0.5f
constexpr int LDT = 68;  // padded LDS stride (floats): keeps 4-float reads 16B-aligned, 2-way bank alias (free)

__global__ __launch_bounds__(256) void rbf_gram_kernel(const float* __restrict__ x,
                                                       float* __restrict__ out,
                                                       int N) {
    __shared__ float As[64 * LDT];   // As[k][row] (transposed tile), rows i0..i0+63
    __shared__ float Bs[64 * LDT];   // Bs[k][col], rows j0..j0+63
    __shared__ float sqA[64], sqB[64];

    const int tid = threadIdx.x;          // 0..255
    const int tx = tid & 15;              // col group
    const int ty = tid >> 4;              // row group
    const int i0 = blockIdx.y * 64;
    const int j0 = blockIdx.x * 64;

    // ---- Stage both 64x64 tiles into LDS, transposed. 4 float4 loads/thread. ----
    const float4* xa = (const float4*)(x + (size_t)i0 * 64);
    const float4* xb = (const float4*)(x + (size_t)j0 * 64);
    #pragma unroll
    for (int it = 0; it < 4; ++it) {
        int q   = it * 256 + tid;   // 0..1023 float4s per tile
        int row = q >> 4;           // 16 float4 per row of 64 floats
        int c4  = q & 15;
        float4 va = xa[row * 16 + c4];
        float4 vb = xb[row * 16 + c4];
        int c = c4 * 4;
        As[(c+0)*LDT + row] = va.x; As[(c+1)*LDT + row] = va.y;
        As[(c+2)*LDT + row] = va.z; As[(c+3)*LDT + row] = va.w;
        Bs[(c+0)*LDT + row] = vb.x; Bs[(c+1)*LDT + row] = vb.y;
        Bs[(c+2)*LDT + row] = vb.z; Bs[(c+3)*LDT + row] = vb.w;
    }
    __syncthreads();

    // ---- Per-row squared norms (threads 0..127 do the 128 sums; conflict-free) ----
    if (tid < 64) {
        float s = 0.f;
        #pragma unroll 16
        for (int k = 0; k < 64; ++k) { float v = As[k*LDT + tid]; s = fmaf(v, v, s); }
        sqA[tid] = s;
    } else if (tid < 128) {
        int t = tid - 64;
        float s = 0.f;
        #pragma unroll 16
        for (int k = 0; k < 64; ++k) { float v = Bs[k*LDT + t]; s = fmaf(v, v, s); }
        sqB[t] = s;
    }
    __syncthreads();

    // ---- Main loop: 4x4 outer-product accumulate over K=64 ----
    float acc[4][4] = {};
    #pragma unroll 8
    for (int k = 0; k < 64; ++k) {
        float4 a = *(const float4*)&As[k*LDT + ty*4];   // ds_read_b128
        float4 b = *(const float4*)&Bs[k*LDT + tx*4];   // ds_read_b128
        float av[4] = {a.x, a.y, a.z, a.w};
        float bv[4] = {b.x, b.y, b.z, b.w};
        #pragma unroll
        for (int m = 0; m < 4; ++m)
            #pragma unroll
            for (int n = 0; n < 4; ++n)
                acc[m][n] = fmaf(av[m], bv[n], acc[m][n]);
    }

    // ---- Epilogue: d2 -> exp, coalesced float4 stores ----
    #pragma unroll
    for (int m = 0; m < 4; ++m) {
        int row = ty*4 + m;
        float sa = sqA[row];
        float4 r;
        float* rp = (float*)&r;
        #pragma unroll
        for (int n = 0; n < 4; ++n) {
            int col = tx*4 + n;
            float d2 = sa + sqB[col] - 2.0f * acc[m][n];
            d2 = fmaxf(d2, 0.0f);
            rp[n] = __expf(-GAMMA * d2);
        }
        *(float4*)&out[(size_t)(i0 + row) * N + (j0 + tx*4)] = r;
    }
}

extern "C" void kernel_launch(void* const* d_in, const int* in_sizes, int n_in,
                              void* d_out, int out_size, void* d_ws, size_t ws_size,
                              hipStream_t stream) {
    (void)n_in; (void)d_ws; (void)ws_size; (void)out_size;
    const float* x = (const float*)d_in[0];
    float* out = (float*)d_out;
    const int K = 64;
    const int N = in_sizes[0] / K;   // 8192
    dim3 grid(N / 64, N / 64);
    rbf_gram_kernel<<<grid, dim3(256), 0, stream>>>(x, out, N);
}